// Round 3
// baseline (269.908 us; speedup 1.0000x reference)
//
#include <hip/hip_runtime.h>

typedef __attribute__((ext_vector_type(8))) short short8;
typedef __attribute__((ext_vector_type(4))) short short4b;
typedef __attribute__((ext_vector_type(4))) float f32x4;

// fp32 -> bf16 bits, round-to-nearest-even (no NaN handling needed here)
static __device__ __forceinline__ short f2bf(float f) {
    unsigned u = __builtin_bit_cast(unsigned, f);
    u += 0x7FFFu + ((u >> 16) & 1u);
    return (short)(u >> 16);
}

// async global->LDS, 16 bytes per lane. lds base must be wave-uniform; HW adds lane*16.
static __device__ __forceinline__ void g2l16(const void* g, void* l) {
    __builtin_amdgcn_global_load_lds(
        (const __attribute__((address_space(1))) unsigned*)g,
        (__attribute__((address_space(3))) unsigned*)l, 16, 0, 0);
}

// ---------------------------------------------------------------------------
// elementwise fp32 -> bf16
__global__ void convert_x(const float* __restrict__ x, short* __restrict__ xb, int n4) {
    int i = blockIdx.x * blockDim.x + threadIdx.x;
    if (i >= n4) return;
    f32x4 v = *(const f32x4*)&x[(long)i * 4];
    short4b o;
    #pragma unroll
    for (int j = 0; j < 4; ++j) o[j] = f2bf(v[j]);
    *(short4b*)&xb[(long)i * 4] = o;
}

// ---------------------------------------------------------------------------
// W [K][N] fp32  ->  Wt [N][K] bf16   (64x64 LDS tile transpose)
__global__ void transpose_conv(const float* __restrict__ W, short* __restrict__ Wt,
                               int K, int N) {
    __shared__ float lds[64][65];
    const int t = threadIdx.x;
    const int n0 = blockIdx.x * 64, k0 = blockIdx.y * 64;
    const int rr = t >> 4, q4 = (t & 15) * 4;
    #pragma unroll
    for (int p = 0; p < 4; ++p) {
        int k = rr + p * 16;
        f32x4 v = *(const f32x4*)&W[(long)(k0 + k) * N + n0 + q4];
        #pragma unroll
        for (int j = 0; j < 4; ++j) lds[k][q4 + j] = v[j];
    }
    __syncthreads();
    #pragma unroll
    for (int p = 0; p < 4; ++p) {
        int nloc = rr + p * 16;
        short4b o;
        #pragma unroll
        for (int j = 0; j < 4; ++j) o[j] = f2bf(lds[q4 + j][nloc]);
        *(short4b*)&Wt[(long)(n0 + nloc) * K + k0 + q4] = o;
    }
}

// ---------------------------------------------------------------------------
// GEMM: C[M,N] = A[M,K] @ Bt[N,K]^T + bias.  A,Bt bf16 row-major.
// 128x128 tile, BK=32, 256 thr (4 waves, 2x2), 16x16x32 MFMA.
// 64B LDS rows are already at the wave64 ds_read_b128 bank floor -> no swizzle.
template<int F32OUT>
__global__ __launch_bounds__(256, 2)
void gemm_bt(const short* __restrict__ A, const short* __restrict__ Bt,
             const float* __restrict__ bias, void* __restrict__ C,
             int M, int N, int K) {
    __shared__ short lA[128 * 32];
    __shared__ short lB[128 * 32];
    const int t = threadIdx.x;
    const int lane = t & 63, w = t >> 6;
    const int m0 = blockIdx.y * 128, n0 = blockIdx.x * 128;
    const int lr = lane & 15, lk = lane >> 4;
    const int wr = w >> 1, wc = w & 1;

    f32x4 acc[4][4];
    #pragma unroll
    for (int i = 0; i < 4; ++i)
        #pragma unroll
        for (int j = 0; j < 4; ++j)
            #pragma unroll
            for (int e = 0; e < 4; ++e) acc[i][j][e] = 0.0f;

    const int nsteps = K >> 5;
    for (int kt = 0; kt < nsteps; ++kt) {
        const int kb = kt * 32;
        #pragma unroll
        for (int c = 0; c < 2; ++c) {
            int off  = c * 4096 + w * 1024;      // wave-uniform byte base in tile
            int offl = off + lane * 16;          // this lane's byte offset (for global addr)
            int ra = offl >> 6;                  // 64 B per LDS row (32 bf16)
            int ca = (offl & 63) >> 1;
            g2l16(A  + (long)(m0 + ra) * K + kb + ca, (short*)lA + (off >> 1));
            g2l16(Bt + (long)(n0 + ra) * K + kb + ca, (short*)lB + (off >> 1));
        }
        __syncthreads();
        short8 af[4], bf[4];
        #pragma unroll
        for (int m = 0; m < 4; ++m)
            af[m] = *(const short8*)&lA[(wr * 64 + m * 16 + lr) * 32 + lk * 8];
        #pragma unroll
        for (int n = 0; n < 4; ++n)
            bf[n] = *(const short8*)&lB[(wc * 64 + n * 16 + lr) * 32 + lk * 8];
        #pragma unroll
        for (int m = 0; m < 4; ++m)
            #pragma unroll
            for (int n = 0; n < 4; ++n)
                acc[m][n] = __builtin_amdgcn_mfma_f32_16x16x32_bf16(af[m], bf[n], acc[m][n], 0, 0, 0);
        __syncthreads();
    }

    #pragma unroll
    for (int n = 0; n < 4; ++n) {
        int col = n0 + wc * 64 + n * 16 + lr;
        float bb = bias[col];
        #pragma unroll
        for (int m = 0; m < 4; ++m) {
            int rowb = m0 + wr * 64 + m * 16 + lk * 4;
            #pragma unroll
            for (int r = 0; r < 4; ++r) {
                float v = acc[m][n][r] + bb;
                if (F32OUT) ((float*)C)[(long)(rowb + r) * N + col] = v;
                else        ((short*)C)[(long)(rowb + r) * N + col] = f2bf(v);
            }
        }
    }
}

// ---------------------------------------------------------------------------
// Vt[b,h,d,s] <- qkv[:, 2048 + h*64 + d]   (64x64 per-tile transpose)
__global__ void build_vt(const short* __restrict__ qkv, short* __restrict__ vt) {
    __shared__ short lds[64][72];
    const int t = threadIdx.x;
    const int st = blockIdx.x, bh = blockIdx.y;
    const int b = bh >> 4, h = bh & 15;
    const int s0 = st * 64;
    const int sr = t >> 3, c8 = (t & 7) * 8;
    #pragma unroll
    for (int p = 0; p < 2; ++p) {
        int s = sr + p * 32;
        short8 v = *(const short8*)&qkv[(long)(b * 2048 + s0 + s) * 3072 + 2048 + h * 64 + c8];
        *(short8*)&lds[s][c8] = v;
    }
    __syncthreads();
    #pragma unroll
    for (int p = 0; p < 2; ++p) {
        int d = sr + p * 32;
        short8 v;
        #pragma unroll
        for (int j = 0; j < 8; ++j) v[j] = lds[c8 + j][d];
        *(short8*)&vt[(long)(bh * 64 + d) * 2048 + s0 + c8] = v;
    }
}

// ---------------------------------------------------------------------------
// Flash causal attention. One block per (128 q-rows, b*16+h). 4 waves x 32 rows.
// Q,K read from qkv (bf16), V from Vt. Writes pre_o [4096][1024] bf16.
//
// LDS tiles have 128B rows (8 x 16B slots). XOR-swizzle: slot' = slot ^ (row&7)
// (byte ^= (row&7)<<4). lK/lV: linear global_load_lds dest + pre-swizzled global
// source column (rule #21); reads apply the same XOR. lP: both ds_write and
// ds_read apply the XOR. Brings 16-way conflicts down to the b128 8-lane floor.
__global__ __launch_bounds__(256, 2)
void attn_kernel(const short* __restrict__ qkv, const short* __restrict__ vt,
                 short* __restrict__ pre_o) {
    __shared__ short lK[64 * 64];
    __shared__ short lV[64 * 64];           // stored [d][k] (swizzled)
    __shared__ short lP[4][32 * 64];        // per-wave P tile (swizzled)
    const int t = threadIdx.x, lane = t & 63, w = t >> 6;
    const int lr = lane & 15, lk = lane >> 4;
    const int qt = blockIdx.x, bh = blockIdx.y;
    const int b = bh >> 4, h = bh & 15;
    const int q0 = qt * 128;

    // Q fragments (rows w*32 + m*16 + lr, k = dk*32 + lk*8)
    short8 aq[2][2];
    #pragma unroll
    for (int m = 0; m < 2; ++m)
        #pragma unroll
        for (int dk = 0; dk < 2; ++dk)
            aq[m][dk] = *(const short8*)&qkv[(long)(b * 2048 + q0 + w * 32 + m * 16 + lr) * 3072
                                             + h * 64 + dk * 32 + lk * 8];

    f32x4 accO[2][4];
    #pragma unroll
    for (int m = 0; m < 2; ++m)
        #pragma unroll
        for (int n = 0; n < 4; ++n)
            #pragma unroll
            for (int e = 0; e < 4; ++e) accO[m][n][e] = 0.0f;
    float mst[2][4], lst[2][4];
    #pragma unroll
    for (int m = 0; m < 2; ++m)
        #pragma unroll
        for (int r = 0; r < 4; ++r) { mst[m][r] = -1e30f; lst[m][r] = 0.0f; }

    // staging geometry (per lane): LDS byte offl -> row r, phys slot; the data
    // that must land there is logical slot (phys ^ (r&7)) of that row.
    const int ntiles = 2 * qt + 2;
    for (int kt = 0; kt < ntiles; ++kt) {
        #pragma unroll
        for (int c = 0; c < 2; ++c) {
            int off   = c * 4096 + w * 1024;
            int offl  = off + lane * 16;
            int r     = offl >> 7;                       // LDS row (128 B rows)
            int slog  = ((offl >> 4) & 7) ^ (r & 7);     // logical 16B slot for this dest
            g2l16(qkv + (long)(b * 2048 + kt * 64 + r) * 3072 + 1024 + h * 64 + slog * 8,
                  (short*)lK + (off >> 1));
            g2l16(vt + (long)(bh * 64 + r) * 2048 + kt * 64 + slog * 8,
                  (short*)lV + (off >> 1));
        }
        __syncthreads();

        // S = Q @ Ktile^T  (each wave: 32 q-rows x 64 keys)
        f32x4 accS[2][4];
        #pragma unroll
        for (int m = 0; m < 2; ++m)
            #pragma unroll
            for (int n = 0; n < 4; ++n)
                #pragma unroll
                for (int e = 0; e < 4; ++e) accS[m][n][e] = 0.0f;
        short8 bk[4][2];
        #pragma unroll
        for (int n = 0; n < 4; ++n)
            #pragma unroll
            for (int dk = 0; dk < 2; ++dk)
                bk[n][dk] = *(const short8*)((const char*)lK + (n * 16 + lr) * 128
                                             + (((dk * 4 + lk) ^ (lr & 7)) << 4));
        #pragma unroll
        for (int m = 0; m < 2; ++m)
            #pragma unroll
            for (int n = 0; n < 4; ++n)
                #pragma unroll
                for (int dk = 0; dk < 2; ++dk)
                    accS[m][n] = __builtin_amdgcn_mfma_f32_16x16x32_bf16(aq[m][dk], bk[n][dk], accS[m][n], 0, 0, 0);

        // online softmax (row lives in 16 consecutive lanes; cols = lane&15)
        #pragma unroll
        for (int m = 0; m < 2; ++m) {
            #pragma unroll
            for (int r = 0; r < 4; ++r) {
                int qrow = q0 + w * 32 + m * 16 + lk * 4 + r;
                float sv[4];
                float mx = -1e30f;
                #pragma unroll
                for (int n = 0; n < 4; ++n) {
                    float s = accS[m][n][r] * 0.125f;
                    int key = kt * 64 + n * 16 + lr;
                    if (key > qrow || s == 0.0f) s = -10000.0f;  // faithful tril+zero-fill
                    sv[n] = s;
                    mx = fmaxf(mx, s);
                }
                mx = fmaxf(mx, __shfl_xor(mx, 1));
                mx = fmaxf(mx, __shfl_xor(mx, 2));
                mx = fmaxf(mx, __shfl_xor(mx, 4));
                mx = fmaxf(mx, __shfl_xor(mx, 8));
                float mnew = fmaxf(mst[m][r], mx);
                float corr = __expf(mst[m][r] - mnew);
                mst[m][r] = mnew;
                float rs = 0.0f;
                #pragma unroll
                for (int n = 0; n < 4; ++n) { float p = __expf(sv[n] - mnew); sv[n] = p; rs += p; }
                rs += __shfl_xor(rs, 1);
                rs += __shfl_xor(rs, 2);
                rs += __shfl_xor(rs, 4);
                rs += __shfl_xor(rs, 8);
                lst[m][r] = lst[m][r] * corr + rs;
                #pragma unroll
                for (int n = 0; n < 4; ++n) accO[m][n][r] *= corr;
                // swizzled P write: row pr, col pc -> byte pr*128 + (pc*2 ^ ((pr&7)<<4))
                int pr = m * 16 + lk * 4 + r;
                int swz = (pr & 7) << 4;
                #pragma unroll
                for (int n = 0; n < 4; ++n) {
                    int pc = n * 16 + lr;
                    *(short*)((char*)&lP[w][0] + pr * 128 + ((pc * 2) ^ swz)) = f2bf(sv[n]);
                }
            }
        }

        // O += P @ Vtile   (both reads swizzled: slot' = slot ^ (row&7))
        short8 ap[2][2], bv[4][2];
        #pragma unroll
        for (int m = 0; m < 2; ++m)
            #pragma unroll
            for (int kk = 0; kk < 2; ++kk)
                ap[m][kk] = *(const short8*)((const char*)&lP[w][0] + (m * 16 + lr) * 128
                                             + (((kk * 4 + lk) ^ (lr & 7)) << 4));
        #pragma unroll
        for (int n = 0; n < 4; ++n)
            #pragma unroll
            for (int kk = 0; kk < 2; ++kk)
                bv[n][kk] = *(const short8*)((const char*)lV + (n * 16 + lr) * 128
                                             + (((kk * 4 + lk) ^ (lr & 7)) << 4));
        #pragma unroll
        for (int m = 0; m < 2; ++m)
            #pragma unroll
            for (int n = 0; n < 4; ++n)
                #pragma unroll
                for (int kk = 0; kk < 2; ++kk)
                    accO[m][n] = __builtin_amdgcn_mfma_f32_16x16x32_bf16(ap[m][kk], bv[n][kk], accO[m][n], 0, 0, 0);
        __syncthreads();
    }

    // epilogue: O /= l, store bf16 into pre_o [4096][1024] (cols h*64+d)
    #pragma unroll
    for (int m = 0; m < 2; ++m) {
        #pragma unroll
        for (int r = 0; r < 4; ++r) {
            int qrow = q0 + w * 32 + m * 16 + lk * 4 + r;
            float inv = 1.0f / lst[m][r];
            #pragma unroll
            for (int n = 0; n < 4; ++n)
                pre_o[(long)(b * 2048 + qrow) * 1024 + h * 64 + n * 16 + lr] =
                    f2bf(accO[m][n][r] * inv);
        }
    }
}

// ---------------------------------------------------------------------------
extern "C" void kernel_launch(void* const* d_in, const int* in_sizes, int n_in,
                              void* d_out, int out_size, void* d_ws, size_t ws_size,
                              hipStream_t stream) {
    const float* x    = (const float*)d_in[0];   // [2,2048,1024]
    const float* Wqkv = (const float*)d_in[1];   // [1024,3072]
    const float* bqkv = (const float*)d_in[2];   // [3072]
    const float* Wo   = (const float*)d_in[3];   // [1024,1024]
    const float* bo   = (const float*)d_in[4];   // [1024]
    float* out = (float*)d_out;                  // [2,2048,1024] fp32

    char* ws = (char*)d_ws;
    short* xb    = (short*)(ws);                       // 4096*1024   bf16 (8 MB)
    short* wqkvT = (short*)(ws + (8L  << 20));         // 3072*1024   (6 MB)
    short* woT   = (short*)(ws + (14L << 20));         // 1024*1024   (2 MB)
    short* qkv   = (short*)(ws + (16L << 20));         // 4096*3072   (24 MB)
    short* vt    = (short*)(ws + (40L << 20));         // 32*64*2048  (8 MB)
    short* preo  = (short*)(ws + (48L << 20));         // 4096*1024   (8 MB)

    convert_x<<<4096, 256, 0, stream>>>(x, xb, 4096 * 1024 / 4);
    transpose_conv<<<dim3(48, 16), 256, 0, stream>>>(Wqkv, wqkvT, 1024, 3072);
    transpose_conv<<<dim3(16, 16), 256, 0, stream>>>(Wo, woT, 1024, 1024);
    gemm_bt<0><<<dim3(24, 32), 256, 0, stream>>>(xb, wqkvT, bqkv, qkv, 4096, 3072, 1024);
    build_vt<<<dim3(32, 32), 256, 0, stream>>>(qkv, vt);
    attn_kernel<<<dim3(16, 32), 256, 0, stream>>>(qkv, vt, preo);
    gemm_bt<1><<<dim3(8, 32), 256, 0, stream>>>(preo, woT, bo, out, 4096, 1024, 1024);
}

// Round 4
// 224.555 us; speedup vs baseline: 1.2020x; 1.2020x over previous
//
#include <hip/hip_runtime.h>

typedef __attribute__((ext_vector_type(8))) short short8;
typedef __attribute__((ext_vector_type(4))) short short4b;
typedef __attribute__((ext_vector_type(4))) float f32x4;

// fp32 -> bf16 bits, round-to-nearest-even (no NaN handling needed here)
static __device__ __forceinline__ short f2bf(float f) {
    unsigned u = __builtin_bit_cast(unsigned, f);
    u += 0x7FFFu + ((u >> 16) & 1u);
    return (short)(u >> 16);
}

// async global->LDS, 16 bytes per lane. lds base must be wave-uniform; HW adds lane*16.
static __device__ __forceinline__ void g2l16(const void* g, void* l) {
    __builtin_amdgcn_global_load_lds(
        (const __attribute__((address_space(1))) unsigned*)g,
        (__attribute__((address_space(3))) unsigned*)l, 16, 0, 0);
}

// ---------------------------------------------------------------------------
// elementwise fp32 -> bf16
__global__ void convert_x(const float* __restrict__ x, short* __restrict__ xb, int n4) {
    int i = blockIdx.x * blockDim.x + threadIdx.x;
    if (i >= n4) return;
    f32x4 v = *(const f32x4*)&x[(long)i * 4];
    short4b o;
    #pragma unroll
    for (int j = 0; j < 4; ++j) o[j] = f2bf(v[j]);
    *(short4b*)&xb[(long)i * 4] = o;
}

// ---------------------------------------------------------------------------
// W [K][N] fp32  ->  Wt [N][K] bf16   (64x64 LDS tile transpose)
__global__ void transpose_conv(const float* __restrict__ W, short* __restrict__ Wt,
                               int K, int N) {
    __shared__ float lds[64][65];
    const int t = threadIdx.x;
    const int n0 = blockIdx.x * 64, k0 = blockIdx.y * 64;
    const int rr = t >> 4, q4 = (t & 15) * 4;
    #pragma unroll
    for (int p = 0; p < 4; ++p) {
        int k = rr + p * 16;
        f32x4 v = *(const f32x4*)&W[(long)(k0 + k) * N + n0 + q4];
        #pragma unroll
        for (int j = 0; j < 4; ++j) lds[k][q4 + j] = v[j];
    }
    __syncthreads();
    #pragma unroll
    for (int p = 0; p < 4; ++p) {
        int nloc = rr + p * 16;
        short4b o;
        #pragma unroll
        for (int j = 0; j < 4; ++j) o[j] = f2bf(lds[q4 + j][nloc]);
        *(short4b*)&Wt[(long)(n0 + nloc) * K + k0 + q4] = o;
    }
}

// ---------------------------------------------------------------------------
// GEMM: C[M,N] = A[M,K] @ Bt[N,K]^T + bias.  A,Bt bf16 row-major.
// 128x128 tile, BK=32, 256 thr (4 waves, 2x2), 16x16x32 MFMA.
// 64B LDS rows are already at the wave64 ds_read_b128 bank floor -> no swizzle.
template<int F32OUT>
__global__ __launch_bounds__(256, 2)
void gemm_bt(const short* __restrict__ A, const short* __restrict__ Bt,
             const float* __restrict__ bias, void* __restrict__ C,
             int M, int N, int K) {
    __shared__ short lA[128 * 32];
    __shared__ short lB[128 * 32];
    const int t = threadIdx.x;
    const int lane = t & 63, w = t >> 6;
    const int m0 = blockIdx.y * 128, n0 = blockIdx.x * 128;
    const int lr = lane & 15, lk = lane >> 4;
    const int wr = w >> 1, wc = w & 1;

    f32x4 acc[4][4];
    #pragma unroll
    for (int i = 0; i < 4; ++i)
        #pragma unroll
        for (int j = 0; j < 4; ++j)
            #pragma unroll
            for (int e = 0; e < 4; ++e) acc[i][j][e] = 0.0f;

    const int nsteps = K >> 5;
    for (int kt = 0; kt < nsteps; ++kt) {
        const int kb = kt * 32;
        #pragma unroll
        for (int c = 0; c < 2; ++c) {
            int off  = c * 4096 + w * 1024;      // wave-uniform byte base in tile
            int offl = off + lane * 16;          // this lane's byte offset (for global addr)
            int ra = offl >> 6;                  // 64 B per LDS row (32 bf16)
            int ca = (offl & 63) >> 1;
            g2l16(A  + (long)(m0 + ra) * K + kb + ca, (short*)lA + (off >> 1));
            g2l16(Bt + (long)(n0 + ra) * K + kb + ca, (short*)lB + (off >> 1));
        }
        __syncthreads();
        short8 af[4], bf[4];
        #pragma unroll
        for (int m = 0; m < 4; ++m)
            af[m] = *(const short8*)&lA[(wr * 64 + m * 16 + lr) * 32 + lk * 8];
        #pragma unroll
        for (int n = 0; n < 4; ++n)
            bf[n] = *(const short8*)&lB[(wc * 64 + n * 16 + lr) * 32 + lk * 8];
        #pragma unroll
        for (int m = 0; m < 4; ++m)
            #pragma unroll
            for (int n = 0; n < 4; ++n)
                acc[m][n] = __builtin_amdgcn_mfma_f32_16x16x32_bf16(af[m], bf[n], acc[m][n], 0, 0, 0);
        __syncthreads();
    }

    #pragma unroll
    for (int n = 0; n < 4; ++n) {
        int col = n0 + wc * 64 + n * 16 + lr;
        float bb = bias[col];
        #pragma unroll
        for (int m = 0; m < 4; ++m) {
            int rowb = m0 + wr * 64 + m * 16 + lk * 4;
            #pragma unroll
            for (int r = 0; r < 4; ++r) {
                float v = acc[m][n][r] + bb;
                if (F32OUT) ((float*)C)[(long)(rowb + r) * N + col] = v;
                else        ((short*)C)[(long)(rowb + r) * N + col] = f2bf(v);
            }
        }
    }
}

// ---------------------------------------------------------------------------
// Vt[b,h,d,s] <- qkv[:, 2048 + h*64 + d]   (64x64 per-tile transpose)
__global__ void build_vt(const short* __restrict__ qkv, short* __restrict__ vt) {
    __shared__ short lds[64][72];
    const int t = threadIdx.x;
    const int st = blockIdx.x, bh = blockIdx.y;
    const int b = bh >> 4, h = bh & 15;
    const int s0 = st * 64;
    const int sr = t >> 3, c8 = (t & 7) * 8;
    #pragma unroll
    for (int p = 0; p < 2; ++p) {
        int s = sr + p * 32;
        short8 v = *(const short8*)&qkv[(long)(b * 2048 + s0 + s) * 3072 + 2048 + h * 64 + c8];
        *(short8*)&lds[s][c8] = v;
    }
    __syncthreads();
    #pragma unroll
    for (int p = 0; p < 2; ++p) {
        int d = sr + p * 32;
        short8 v;
        #pragma unroll
        for (int j = 0; j < 8; ++j) v[j] = lds[c8 + j][d];
        *(short8*)&vt[(long)(bh * 64 + d) * 2048 + s0 + c8] = v;
    }
}

// ---------------------------------------------------------------------------
// Flash causal attention, load-balanced + double-buffered.
// QBLK=64 (4 waves x 16 q-rows), KVBLK=64. Block = pair index p in [0,16):
// processes q-tiles Q=p (p+1 key tiles) then Q=31-p (32-p key tiles) ->
// exactly 33 iterations for every block (uniform work across all 512 blocks).
// 2-phase pipeline: stage(next) -> compute(cur) -> barrier (T3-minimum).
// LDS tiles: 128B rows, XOR swizzle slot' = slot ^ (row&7); lK/lV staged via
// linear-dest global_load_lds with pre-swizzled global source (rule #21).
__global__ __launch_bounds__(256, 2)
void attn_kernel(const short* __restrict__ qkv, const short* __restrict__ vt,
                 short* __restrict__ pre_o) {
    __shared__ short lK[2][64 * 64];
    __shared__ short lV[2][64 * 64];        // stored [d][k] (swizzled)
    __shared__ short lP[4][16 * 64];        // per-wave P tile (swizzled)
    const int t = threadIdx.x, lane = t & 63, w = t >> 6;
    const int lr = lane & 15, lk = lane >> 4;
    const int pidx = blockIdx.x, bh = blockIdx.y;
    const int b = bh >> 4, h = bh & 15;

    // per-lane staging geometry (two 4KB chunks per 8KB tile)
    int soff[2], sK_row[2], sslot[2];
    #pragma unroll
    for (int c = 0; c < 2; ++c) {
        int off  = c * 4096 + w * 1024;
        int offl = off + lane * 16;
        int r    = offl >> 7;                       // row within 64-row tile
        soff[c]  = off >> 1;                        // short index of chunk base
        sK_row[c] = r;
        sslot[c] = (((offl >> 4) & 7) ^ (r & 7)) * 8;  // logical bf16 col for this dest
    }

    #pragma unroll 1
    for (int seg = 0; seg < 2; ++seg) {
        const int Q  = seg ? (31 - pidx) : pidx;
        const int q0 = Q * 64;
        const int nt = seg ? (32 - pidx) : (pidx + 1);

        // Q fragments (rows q0 + w*16 + lr, k = dk*32 + lk*8)
        short8 aq[2];
        #pragma unroll
        for (int dk = 0; dk < 2; ++dk)
            aq[dk] = *(const short8*)&qkv[(long)(b * 2048 + q0 + w * 16 + lr) * 3072
                                          + h * 64 + dk * 32 + lk * 8];

        f32x4 accO[4];
        #pragma unroll
        for (int n = 0; n < 4; ++n)
            #pragma unroll
            for (int e = 0; e < 4; ++e) accO[n][e] = 0.0f;
        float mst[4], lst[4];
        #pragma unroll
        for (int r = 0; r < 4; ++r) { mst[r] = -1e30f; lst[r] = 0.0f; }

        // prologue: stage tile 0 into buf 0
        #pragma unroll
        for (int c = 0; c < 2; ++c) {
            g2l16(qkv + (long)(b * 2048 + 0 * 64 + sK_row[c]) * 3072 + 1024 + h * 64 + sslot[c],
                  &lK[0][soff[c]]);
            g2l16(vt + (long)(bh * 64 + sK_row[c]) * 2048 + 0 * 64 + sslot[c],
                  &lV[0][soff[c]]);
        }
        __syncthreads();

        #pragma unroll 1
        for (int kt = 0; kt < nt; ++kt) {
            const int cur = kt & 1;
            // stage next tile into the other buffer (loads fly during compute)
            if (kt + 1 < nt) {
                #pragma unroll
                for (int c = 0; c < 2; ++c) {
                    g2l16(qkv + (long)(b * 2048 + (kt + 1) * 64 + sK_row[c]) * 3072
                              + 1024 + h * 64 + sslot[c],
                          &lK[cur ^ 1][soff[c]]);
                    g2l16(vt + (long)(bh * 64 + sK_row[c]) * 2048 + (kt + 1) * 64 + sslot[c],
                          &lV[cur ^ 1][soff[c]]);
                }
            }

            // S = Q @ Ktile^T  (wave: 16 q-rows x 64 keys)
            f32x4 accS[4];
            #pragma unroll
            for (int n = 0; n < 4; ++n)
                #pragma unroll
                for (int e = 0; e < 4; ++e) accS[n][e] = 0.0f;
            short8 bk[4][2];
            #pragma unroll
            for (int n = 0; n < 4; ++n)
                #pragma unroll
                for (int dk = 0; dk < 2; ++dk)
                    bk[n][dk] = *(const short8*)((const char*)&lK[cur][0] + (n * 16 + lr) * 128
                                                 + (((dk * 4 + lk) ^ (lr & 7)) << 4));
            #pragma unroll
            for (int n = 0; n < 4; ++n)
                #pragma unroll
                for (int dk = 0; dk < 2; ++dk)
                    accS[n] = __builtin_amdgcn_mfma_f32_16x16x32_bf16(aq[dk], bk[n][dk], accS[n], 0, 0, 0);

            // online softmax (row lives in 16 consecutive lanes; cols = lane&15)
            #pragma unroll
            for (int r = 0; r < 4; ++r) {
                int qrow = q0 + w * 16 + lk * 4 + r;
                float sv[4];
                float mx = -1e30f;
                #pragma unroll
                for (int n = 0; n < 4; ++n) {
                    float s = accS[n][r] * 0.125f;
                    int key = kt * 64 + n * 16 + lr;
                    if (key > qrow || s == 0.0f) s = -10000.0f;  // faithful tril+zero-fill
                    sv[n] = s;
                    mx = fmaxf(mx, s);
                }
                mx = fmaxf(mx, __shfl_xor(mx, 1));
                mx = fmaxf(mx, __shfl_xor(mx, 2));
                mx = fmaxf(mx, __shfl_xor(mx, 4));
                mx = fmaxf(mx, __shfl_xor(mx, 8));
                float mnew = fmaxf(mst[r], mx);
                float corr = __expf(mst[r] - mnew);
                mst[r] = mnew;
                float rs = 0.0f;
                #pragma unroll
                for (int n = 0; n < 4; ++n) { float p = __expf(sv[n] - mnew); sv[n] = p; rs += p; }
                rs += __shfl_xor(rs, 1);
                rs += __shfl_xor(rs, 2);
                rs += __shfl_xor(rs, 4);
                rs += __shfl_xor(rs, 8);
                lst[r] = lst[r] * corr + rs;
                #pragma unroll
                for (int n = 0; n < 4; ++n) accO[n][r] *= corr;
                // swizzled P write: row pr, col pc -> byte pr*128 + (pc*2 ^ ((pr&7)<<4))
                int prr = lk * 4 + r;
                int swz = (prr & 7) << 4;
                #pragma unroll
                for (int n = 0; n < 4; ++n) {
                    int pc = n * 16 + lr;
                    *(short*)((char*)&lP[w][0] + prr * 128 + ((pc * 2) ^ swz)) = f2bf(sv[n]);
                }
            }

            // O += P @ Vtile   (reads swizzled: slot' = slot ^ (row&7))
            short8 ap[2], bv[4][2];
            #pragma unroll
            for (int kk = 0; kk < 2; ++kk)
                ap[kk] = *(const short8*)((const char*)&lP[w][0] + lr * 128
                                          + (((kk * 4 + lk) ^ (lr & 7)) << 4));
            #pragma unroll
            for (int n = 0; n < 4; ++n)
                #pragma unroll
                for (int kk = 0; kk < 2; ++kk)
                    bv[n][kk] = *(const short8*)((const char*)&lV[cur][0] + (n * 16 + lr) * 128
                                                 + (((kk * 4 + lk) ^ (lr & 7)) << 4));
            #pragma unroll
            for (int n = 0; n < 4; ++n)
                #pragma unroll
                for (int kk = 0; kk < 2; ++kk)
                    accO[n] = __builtin_amdgcn_mfma_f32_16x16x32_bf16(ap[kk], bv[n][kk], accO[n], 0, 0, 0);

            __syncthreads();   // drains vmcnt (next tile ready) + fences buffer reuse
        }

        // epilogue: O /= l, store bf16 into pre_o [4096][1024] (cols h*64+d)
        #pragma unroll
        for (int r = 0; r < 4; ++r) {
            int qrow = q0 + w * 16 + lk * 4 + r;
            float inv = 1.0f / lst[r];
            #pragma unroll
            for (int n = 0; n < 4; ++n)
                pre_o[(long)(b * 2048 + qrow) * 1024 + h * 64 + n * 16 + lr] =
                    f2bf(accO[n][r] * inv);
        }
    }
}

// ---------------------------------------------------------------------------
extern "C" void kernel_launch(void* const* d_in, const int* in_sizes, int n_in,
                              void* d_out, int out_size, void* d_ws, size_t ws_size,
                              hipStream_t stream) {
    const float* x    = (const float*)d_in[0];   // [2,2048,1024]
    const float* Wqkv = (const float*)d_in[1];   // [1024,3072]
    const float* bqkv = (const float*)d_in[2];   // [3072]
    const float* Wo   = (const float*)d_in[3];   // [1024,1024]
    const float* bo   = (const float*)d_in[4];   // [1024]
    float* out = (float*)d_out;                  // [2,2048,1024] fp32

    char* ws = (char*)d_ws;
    short* xb    = (short*)(ws);                       // 4096*1024   bf16 (8 MB)
    short* wqkvT = (short*)(ws + (8L  << 20));         // 3072*1024   (6 MB)
    short* woT   = (short*)(ws + (14L << 20));         // 1024*1024   (2 MB)
    short* qkv   = (short*)(ws + (16L << 20));         // 4096*3072   (24 MB)
    short* vt    = (short*)(ws + (40L << 20));         // 32*64*2048  (8 MB)
    short* preo  = (short*)(ws + (48L << 20));         // 4096*1024   (8 MB)

    convert_x<<<4096, 256, 0, stream>>>(x, xb, 4096 * 1024 / 4);
    transpose_conv<<<dim3(48, 16), 256, 0, stream>>>(Wqkv, wqkvT, 1024, 3072);
    transpose_conv<<<dim3(16, 16), 256, 0, stream>>>(Wo, woT, 1024, 1024);
    gemm_bt<0><<<dim3(24, 32), 256, 0, stream>>>(xb, wqkvT, bqkv, qkv, 4096, 3072, 1024);
    build_vt<<<dim3(32, 32), 256, 0, stream>>>(qkv, vt);
    attn_kernel<<<dim3(16, 32), 256, 0, stream>>>(qkv, vt, preo);
    gemm_bt<1><<<dim3(8, 32), 256, 0, stream>>>(preo, woT, bo, out, 4096, 1024, 1024);
}